// Round 2
// baseline (1102.068 us; speedup 1.0000x reference)
//
#include <hip/hip_runtime.h>

typedef __bf16 bf16_t;
typedef __bf16 bf16x8 __attribute__((ext_vector_type(8)));
typedef float f32x4 __attribute__((ext_vector_type(4)));
typedef float f32x16 __attribute__((ext_vector_type(16)));

#define TILE_E 64
#define CSTR 168   // combined view stride (bf16): 145 used + pad (336B, 16B-aligned rows)
#define HS2  392   // H view stride (bf16): 384 cols + 8 pad (784B, 16B-aligned rows)

// ws layout in bf16 elems: 144 fragment chunks of 512, then x_bf
#define W2X_OFF (120 * 512)
#define W2P_OFF (136 * 512)
#define W2E_OFF (140 * 512)
#define XBF_OFF (144 * 512)

// ---------------- weight fragment prep ----------------
// chunk = 1KB = 64 lanes x 16B; main kernel's B-fragment load is one dwordx4/lane.
// W1all = concat cols [W1x | W1p | W1e] -> 384 cols = 12 col-tiles (ctg), k=160 (145 + bias@145 + pad).
__global__ void prep_w(const float* __restrict__ W1x, const float* __restrict__ b1x,
                       const float* __restrict__ W1p, const float* __restrict__ b1p,
                       const float* __restrict__ W1e, const float* __restrict__ b1e,
                       const float* __restrict__ W2x, const float* __restrict__ W2p,
                       const float* __restrict__ W2e, bf16_t* __restrict__ wf)
{
    const int cid = blockIdx.x;      // 0..143
    const int lane = threadIdx.x;    // 0..63
    float v[8];
    if (cid < 120) {
        // W1all frags: cid = ctg*10 + kk; B 32x32x16: n=lane&31, k=kk*16+(lane>>5)*8+j
        const int ctg = cid / 10, kk = cid % 10;
        const int m = ctg >> 2;
        const float* W1 = (m == 0) ? W1x : ((m == 1) ? W1p : W1e);
        const float* b1 = (m == 0) ? b1x : ((m == 1) ? b1p : b1e);
        const int n = (ctg & 3) * 32 + (lane & 31);
        const int kb = kk * 16 + (lane >> 5) * 8;
#pragma unroll
        for (int j = 0; j < 8; ++j) {
            const int k = kb + j;
            v[j] = (k < 145) ? W1[k * 128 + n] : ((k == 145) ? b1[n] : 0.0f);
        }
    } else if (cid < 136) {
        // W2x frags: (ct2, kk); 32x32x16 B
        const int c2 = cid - 120, ct2 = c2 / 8, kk = c2 % 8;
        const int n = ct2 * 32 + (lane & 31);
        const int kb = kk * 16 + (lane >> 5) * 8;
#pragma unroll
        for (int j = 0; j < 8; ++j) v[j] = W2x[(kb + j) * 64 + n];
    } else if (cid < 140) {
        // W2p frags: 16x16x32 B: n=lane&15 (only col 0 real), k=kk*32+(lane>>4)*8+j
        const int kk = cid - 136;
        const int n = lane & 15;
        const int kb = kk * 32 + (lane >> 4) * 8;
#pragma unroll
        for (int j = 0; j < 8; ++j) v[j] = (n == 0) ? W2p[kb + j] : 0.0f;
    } else {
        // W2e frags: 16x16x32 B
        const int kk = cid - 140;
        const int n = lane & 15;
        const int kb = kk * 32 + (lane >> 4) * 8;
#pragma unroll
        for (int j = 0; j < 8; ++j) v[j] = W2e[(kb + j) * 16 + n];
    }
    bf16x8 o;
#pragma unroll
    for (int j = 0; j < 8; ++j) o[j] = (bf16_t)v[j];
    *(bf16x8*)(wf + (long)cid * 512 + lane * 8) = o;
}

// ---------------- x -> bf16 ----------------
__global__ void prep_x_kernel(const float* __restrict__ x, bf16_t* __restrict__ xbf, int n8)
{
    const int i = blockIdx.x * blockDim.x + threadIdx.x;
    if (i < n8) {
        const float4* p = (const float4*)x + (long)i * 2;
        float4 a = p[0], b = p[1];
        bf16x8 v;
        v[0] = (bf16_t)a.x; v[1] = (bf16_t)a.y; v[2] = (bf16_t)a.z; v[3] = (bf16_t)a.w;
        v[4] = (bf16_t)b.x; v[5] = (bf16_t)b.y; v[6] = (bf16_t)b.z; v[7] = (bf16_t)b.w;
        ((bf16x8*)xbf)[i] = v;
    }
}

// ---------------- fused main kernel ----------------
// Phase 1: stage combined[64x160] (stride CSTR) in s_buf.         [sync]
// Phase 2: one fused L1 GEMM 64x160x384; wave w owns col-tiles 3w..3w+2. [sync: LDS reads done]
// Phase 3: SiLU, overwrite s_buf with H[64x384] (stride HS2).     [sync]
// Phase 4: L2 in parallel: waves 0/1 msg_x (32x32), wave 2 pos, wave 3 edge (16x16).
//          All atomics at the very end, NO trailing barrier -> drain overlaps next block.
__global__ __launch_bounds__(256, 3)
void egnn_main(const float* __restrict__ x, const float* __restrict__ pos,
               const float* __restrict__ ea, const int* __restrict__ eidx,
               const float* __restrict__ b2x, const float* __restrict__ b2p,
               const float* __restrict__ b2e,
               const bf16_t* __restrict__ wf, const bf16_t* __restrict__ xbf,
               float* __restrict__ aggx, float* __restrict__ aggpos,
               float* __restrict__ eup, int N, int E)
{
    __shared__ __align__(16) bf16_t s_buf[TILE_E * HS2];   // combined view then H view
    __shared__ float s_rel[TILE_E][3];
    __shared__ int s_col[TILE_E];

    const int tid = threadIdx.x;
    const int lane = tid & 63;
    const int wv = tid >> 6;        // 0..3
    const long e0 = (long)blockIdx.x * TILE_E;

    // ---- Phase 1a: indices, rel_pos, dist_sq, bias-one, K-pad ----
    if (tid < TILE_E) {
        long e = e0 + tid;
        int r = 0, c = 0;
        if (e < E) { r = eidx[e]; c = eidx[(long)E + e]; }
        s_col[tid] = c;
        float ax = 0.f, ay = 0.f, az = 0.f;
        if (e < E) {
            const float* pr = pos + (long)r * 3;
            const float* pc = pos + (long)c * 3;
            ax = pr[0] - pc[0]; ay = pr[1] - pc[1]; az = pr[2] - pc[2];
        }
        s_rel[tid][0] = ax; s_rel[tid][1] = ay; s_rel[tid][2] = az;
        bf16_t* cr = s_buf + tid * CSTR;
        cr[144] = (bf16_t)(ax * ax + ay * ay + az * az);
        cr[145] = (bf16_t)1.0f;   // bias row (W1all frag k==145 holds b1)
#pragma unroll
        for (int p = 146; p < 160; ++p) cr[p] = (bf16_t)0.0f;
    }

    // ---- Phase 1b: x[row], x[col], edge_attr -> combined (bf16) ----
    {
        const int el = tid >> 2, q = tid & 3;   // 4 threads per edge
        long e = e0 + el;
        int r = 0, c = 0;
        if (e < E) { r = eidx[e]; c = eidx[(long)E + e]; }
        bf16_t* dst = s_buf + el * CSTR;
        if (xbf) {
            const uint4* pr = (const uint4*)(xbf + (long)r * 64) + q * 2;
            const uint4* pc = (const uint4*)(xbf + (long)c * 64) + q * 2;
            uint4 a0 = pr[0], a1 = pr[1], c0 = pc[0], c1 = pc[1];
            uint4* d0 = (uint4*)(dst + q * 16);
            d0[0] = a0; d0[1] = a1;
            uint4* d1 = (uint4*)(dst + 64 + q * 16);
            d1[0] = c0; d1[1] = c1;
        } else {
            const float4* pr = (const float4*)(x + (long)r * 64) + q * 4;
            const float4* pc = (const float4*)(x + (long)c * 64) + q * 4;
            bf16_t* d0 = dst + q * 16;
            bf16_t* d1 = dst + 64 + q * 16;
#pragma unroll
            for (int i = 0; i < 4; ++i) {
                float4 v = pr[i];
                d0[i * 4 + 0] = (bf16_t)v.x; d0[i * 4 + 1] = (bf16_t)v.y;
                d0[i * 4 + 2] = (bf16_t)v.z; d0[i * 4 + 3] = (bf16_t)v.w;
            }
#pragma unroll
            for (int i = 0; i < 4; ++i) {
                float4 v = pc[i];
                d1[i * 4 + 0] = (bf16_t)v.x; d1[i * 4 + 1] = (bf16_t)v.y;
                d1[i * 4 + 2] = (bf16_t)v.z; d1[i * 4 + 3] = (bf16_t)v.w;
            }
        }
        float4 v = {0.f, 0.f, 0.f, 0.f};
        if (e < E) v = ((const float4*)(ea + (long)e * 16))[q];
        bf16_t* da = dst + 128 + q * 4;
        da[0] = (bf16_t)v.x; da[1] = (bf16_t)v.y; da[2] = (bf16_t)v.z; da[3] = (bf16_t)v.w;
    }
    __syncthreads();   // barrier 1: combined staged

    // ---- Phase 2: fused L1, 64x160x384 ----
    f32x16 acc[3][2] = {};
    {
        const bf16_t* ar0 = s_buf + (lane & 31) * CSTR + (lane >> 5) * 8;
        const bf16_t* ar1 = ar0 + 32 * CSTR;
#pragma unroll
        for (int ct = 0; ct < 3; ++ct) {
            const bf16_t* bb = wf + (long)((wv * 3 + ct) * 10) * 512 + lane * 8;
            bf16x8 B[10];
#pragma unroll
            for (int kk = 0; kk < 10; ++kk) B[kk] = *(const bf16x8*)(bb + kk * 512);
#pragma unroll
            for (int kk = 0; kk < 10; ++kk) {
                bf16x8 a0 = *(const bf16x8*)(ar0 + kk * 16);
                bf16x8 a1 = *(const bf16x8*)(ar1 + kk * 16);
                acc[ct][0] = __builtin_amdgcn_mfma_f32_32x32x16_bf16(a0, B[kk], acc[ct][0], 0, 0, 0);
                acc[ct][1] = __builtin_amdgcn_mfma_f32_32x32x16_bf16(a1, B[kk], acc[ct][1], 0, 0, 0);
            }
        }
    }
    __syncthreads();   // barrier 2: all L1 LDS reads done, s_buf reusable

    // ---- Phase 3: SiLU -> H (in-place over s_buf, stride HS2) ----
    {
        const int rbase = 4 * (lane >> 5);
#pragma unroll
        for (int ct = 0; ct < 3; ++ct) {
            const int col = (wv * 3 + ct) * 32 + (lane & 31);
#pragma unroll
            for (int half = 0; half < 2; ++half) {
#pragma unroll
                for (int g = 0; g < 16; ++g) {
                    const int row = half * 32 + rbase + (g & 3) + 8 * (g >> 2);
                    float h = acc[ct][half][g];
                    float s = h * __builtin_amdgcn_rcpf(1.0f + __builtin_amdgcn_exp2f(-1.44269504f * h));
                    s_buf[row * HS2 + col] = (bf16_t)s;
                }
            }
        }
    }
    __syncthreads();   // barrier 3: H ready (last barrier in kernel)

    // ---- Phase 4: L2 per-wave + epilogues (atomics dead last) ----
    if (wv < 2) {
        // msg_x: H[:, 0:128] @ W2x -> [64 x 64]; wave wv owns out-cols wv*32..+32
        f32x16 a0 = {0.0f}, a1 = {0.0f};
        const bf16_t* bb = wf + W2X_OFF + (long)(wv * 8) * 512 + lane * 8;
        const bf16_t* ar = s_buf + (lane & 31) * HS2 + (lane >> 5) * 8;
#pragma unroll
        for (int kk = 0; kk < 8; ++kk) {
            bf16x8 b = *(const bf16x8*)(bb + kk * 512);
            bf16x8 av0 = *(const bf16x8*)(ar + kk * 16);
            bf16x8 av1 = *(const bf16x8*)(ar + 32 * HS2 + kk * 16);
            a0 = __builtin_amdgcn_mfma_f32_32x32x16_bf16(av0, b, a0, 0, 0, 0);
            a1 = __builtin_amdgcn_mfma_f32_32x32x16_bf16(av1, b, a1, 0, 0, 0);
        }
        const int oc = wv * 32 + (lane & 31);
        const float bias = b2x[oc];
        const int rb = 4 * (lane >> 5);
#pragma unroll
        for (int g = 0; g < 16; ++g) {
            const int row = rb + (g & 3) + 8 * (g >> 2);
            long e = e0 + row;
            if (e < E) atomicAdd(aggx + (long)s_col[row] * 64 + oc, a0[g] + bias);
        }
#pragma unroll
        for (int g = 0; g < 16; ++g) {
            const int row = 32 + rb + (g & 3) + 8 * (g >> 2);
            long e = e0 + row;
            if (e < E) atomicAdd(aggx + (long)s_col[row] * 64 + oc, a1[g] + bias);
        }
    } else if (wv == 2) {
        // pos weight: H[:, 128:256] @ W2p -> [64 x 1] via 16x16x32 (col 0 real)
        const bf16_t* bb = wf + W2P_OFF + lane * 8;
        bf16x8 Bp[4];
#pragma unroll
        for (int kk = 0; kk < 4; ++kk) Bp[kk] = *(const bf16x8*)(bb + kk * 512);
        const float bias = b2p[0];
#pragma unroll
        for (int rt = 0; rt < 4; ++rt) {
            f32x4 acc4 = {0.0f};
            const bf16_t* ar = s_buf + (rt * 16 + (lane & 15)) * HS2 + 128 + (lane >> 4) * 8;
#pragma unroll
            for (int kk = 0; kk < 4; ++kk) {
                bf16x8 a = *(const bf16x8*)(ar + kk * 32);
                acc4 = __builtin_amdgcn_mfma_f32_16x16x32_bf16(a, Bp[kk], acc4, 0, 0, 0);
            }
            if ((lane & 15) == 0) {
#pragma unroll
                for (int j = 0; j < 4; ++j) {
                    const int row = rt * 16 + (lane >> 4) * 4 + j;
                    long e = e0 + row;
                    if (e < E) {
                        const float w = acc4[j] + bias;
                        const long c3 = (long)s_col[row] * 3;
                        atomicAdd(aggpos + c3 + 0, w * s_rel[row][0]);
                        atomicAdd(aggpos + c3 + 1, w * s_rel[row][1]);
                        atomicAdd(aggpos + c3 + 2, w * s_rel[row][2]);
                    }
                }
            }
        }
    } else {
        // edge_update: H[:, 256:384] @ W2e -> [64 x 16] via 16x16x32
        const bf16_t* bb = wf + W2E_OFF + lane * 8;
        bf16x8 Be[4];
#pragma unroll
        for (int kk = 0; kk < 4; ++kk) Be[kk] = *(const bf16x8*)(bb + kk * 512);
        const float bias = b2e[lane & 15];
#pragma unroll
        for (int rt = 0; rt < 4; ++rt) {
            f32x4 acc4 = {0.0f};
            const bf16_t* ar = s_buf + (rt * 16 + (lane & 15)) * HS2 + 256 + (lane >> 4) * 8;
#pragma unroll
            for (int kk = 0; kk < 4; ++kk) {
                bf16x8 a = *(const bf16x8*)(ar + kk * 32);
                acc4 = __builtin_amdgcn_mfma_f32_16x16x32_bf16(a, Be[kk], acc4, 0, 0, 0);
            }
#pragma unroll
            for (int j = 0; j < 4; ++j) {
                const int row = rt * 16 + (lane >> 4) * 4 + j;
                long e = e0 + row;
                if (e < E) eup[e * 16 + (lane & 15)] = acc4[j] + bias;
            }
        }
    }
    // no trailing barrier: atomic/store drain overlaps the next block's staging
}

extern "C" void kernel_launch(void* const* d_in, const int* in_sizes, int n_in,
                              void* d_out, int out_size, void* d_ws, size_t ws_size,
                              hipStream_t stream)
{
    const float* x   = (const float*)d_in[0];
    const float* pos = (const float*)d_in[1];
    const float* ea  = (const float*)d_in[2];
    const int*   eidx= (const int*)d_in[3];
    const float* W1x = (const float*)d_in[4];
    const float* b1x = (const float*)d_in[5];
    const float* W2x = (const float*)d_in[6];
    const float* b2x = (const float*)d_in[7];
    const float* W1p = (const float*)d_in[8];
    const float* b1p = (const float*)d_in[9];
    const float* W2p = (const float*)d_in[10];
    const float* b2p = (const float*)d_in[11];
    const float* W1e = (const float*)d_in[12];
    const float* b1e = (const float*)d_in[13];
    const float* W2e = (const float*)d_in[14];
    const float* b2e = (const float*)d_in[15];

    const int N = in_sizes[0] / 64;     // node count
    const int E = in_sizes[2] / 16;     // edge count

    bf16_t* wf = (bf16_t*)d_ws;
    const size_t need_xbf = (size_t)XBF_OFF * 2 + (size_t)N * 64 * 2;
    bf16_t* xbf = (ws_size >= need_xbf) ? (wf + XBF_OFF) : nullptr;

    float* aggx = (float*)d_out;
    float* aggp = aggx + (long)N * 64;
    float* eup  = aggp + (long)N * 3;

    // zero the scatter-add output regions (harness poisons d_out)
    hipMemsetAsync(d_out, 0, (size_t)(N * 64 + N * 3) * sizeof(float), stream);

    hipLaunchKernelGGL(prep_w, dim3(144), dim3(64), 0, stream,
                       W1x, b1x, W1p, b1p, W1e, b1e, W2x, W2p, W2e, wf);
    if (xbf) {
        const int n8 = (N * 64) / 8;
        hipLaunchKernelGGL(prep_x_kernel, dim3((n8 + 255) / 256), dim3(256), 0, stream,
                           x, xbf, n8);
    }
    const int tiles = (E + TILE_E - 1) / TILE_E;
    hipLaunchKernelGGL(egnn_main, dim3(tiles), dim3(256), 0, stream,
                       x, pos, ea, eidx, b2x, b2p, b2e, wf, xbf, aggx, aggp, eup, N, E);
}

// Round 3
// 812.627 us; speedup vs baseline: 1.3562x; 1.3562x over previous
//
#include <hip/hip_runtime.h>

typedef __bf16 bf16_t;
typedef __bf16 bf16x8 __attribute__((ext_vector_type(8)));
typedef float f32x4 __attribute__((ext_vector_type(4)));
typedef float f32x16 __attribute__((ext_vector_type(16)));

#define TILE_E 64
#define CSTR 168   // combined LDS row stride (bf16): 145 used + pad; 336B rows
#define HSTR 136   // H LDS row stride (bf16): 272B rows

// ws layout in bf16 elems: 144 fragment chunks of 512, then x_bf
#define W2X_OFF (120 * 512)
#define W2P_OFF (136 * 512)
#define W2E_OFF (140 * 512)
#define XBF_OFF (144 * 512)

// ---------------- weight fragment prep (round-1 layout) ----------------
__global__ void prep_w(const float* __restrict__ W1x, const float* __restrict__ b1x,
                       const float* __restrict__ W1p, const float* __restrict__ b1p,
                       const float* __restrict__ W1e, const float* __restrict__ b1e,
                       const float* __restrict__ W2x, const float* __restrict__ W2p,
                       const float* __restrict__ W2e, bf16_t* __restrict__ wf)
{
    const int cid = blockIdx.x;      // 0..143
    const int lane = threadIdx.x;    // 0..63
    float v[8];
    if (cid < 120) {
        // W1 frags: (mlp, ct, kk); B 32x32x16: n=lane&31, k=kk*16+(lane>>5)*8+j
        const int m = cid / 40, rem = cid % 40, ct = rem / 10, kk = rem % 10;
        const float* W1 = (m == 0) ? W1x : ((m == 1) ? W1p : W1e);
        const float* b1 = (m == 0) ? b1x : ((m == 1) ? b1p : b1e);
        const int n = ct * 32 + (lane & 31);
        const int kb = kk * 16 + (lane >> 5) * 8;
#pragma unroll
        for (int j = 0; j < 8; ++j) {
            const int k = kb + j;
            v[j] = (k < 145) ? W1[k * 128 + n] : ((k == 145) ? b1[n] : 0.0f);
        }
    } else if (cid < 136) {
        const int c2 = cid - 120, ct2 = c2 / 8, kk = c2 % 8;
        const int n = ct2 * 32 + (lane & 31);
        const int kb = kk * 16 + (lane >> 5) * 8;
#pragma unroll
        for (int j = 0; j < 8; ++j) v[j] = W2x[(kb + j) * 64 + n];
    } else if (cid < 140) {
        const int kk = cid - 136;
        const int n = lane & 15;
        const int kb = kk * 32 + (lane >> 4) * 8;
#pragma unroll
        for (int j = 0; j < 8; ++j) v[j] = (n == 0) ? W2p[kb + j] : 0.0f;
    } else {
        const int kk = cid - 140;
        const int n = lane & 15;
        const int kb = kk * 32 + (lane >> 4) * 8;
#pragma unroll
        for (int j = 0; j < 8; ++j) v[j] = W2e[(kb + j) * 16 + n];
    }
    bf16x8 o;
#pragma unroll
    for (int j = 0; j < 8; ++j) o[j] = (bf16_t)v[j];
    *(bf16x8*)(wf + (long)cid * 512 + lane * 8) = o;
}

// ---------------- x -> bf16 ----------------
__global__ void prep_x_kernel(const float* __restrict__ x, bf16_t* __restrict__ xbf, int n8)
{
    const int i = blockIdx.x * blockDim.x + threadIdx.x;
    if (i < n8) {
        const float4* p = (const float4*)x + (long)i * 2;
        float4 a = p[0], b = p[1];
        bf16x8 v;
        v[0] = (bf16_t)a.x; v[1] = (bf16_t)a.y; v[2] = (bf16_t)a.z; v[3] = (bf16_t)a.w;
        v[4] = (bf16_t)b.x; v[5] = (bf16_t)b.y; v[6] = (bf16_t)b.z; v[7] = (bf16_t)b.w;
        ((bf16x8*)xbf)[i] = v;
    }
}

// L1 for MLP m: 64x160x128 GEMM + SiLU -> s_H. Wave owns hid cols [wv*32, wv*32+32).
#define L1_PHASE(mconst)                                                           \
    do {                                                                           \
        f32x16 acc0 = {0.0f};                                                      \
        f32x16 acc1 = {0.0f};                                                      \
        const bf16_t* ar0 = s_comb + (lane & 31) * CSTR + (lane >> 5) * 8;         \
        const bf16_t* ar1 = ar0 + 32 * CSTR;                                       \
        const bf16_t* bb = wf + (long)(((mconst) * 4 + wv) * 10) * 512 + lane * 8; \
        bf16x8 B[10];                                                              \
        _Pragma("unroll")                                                          \
        for (int kk = 0; kk < 10; ++kk) B[kk] = *(const bf16x8*)(bb + kk * 512);   \
        _Pragma("unroll")                                                          \
        for (int kk = 0; kk < 10; ++kk) {                                          \
            bf16x8 a0 = *(const bf16x8*)(ar0 + kk * 16);                           \
            bf16x8 a1 = *(const bf16x8*)(ar1 + kk * 16);                           \
            acc0 = __builtin_amdgcn_mfma_f32_32x32x16_bf16(a0, B[kk], acc0, 0, 0, 0); \
            acc1 = __builtin_amdgcn_mfma_f32_32x32x16_bf16(a1, B[kk], acc1, 0, 0, 0); \
        }                                                                          \
        const int col = wv * 32 + (lane & 31);                                     \
        const int rbase = 4 * (lane >> 5);                                         \
        _Pragma("unroll")                                                          \
        for (int g = 0; g < 16; ++g) {                                             \
            const int row = rbase + (g & 3) + 8 * (g >> 2);                        \
            float h = acc0[g];                                                     \
            s_H[row * HSTR + col] =                                                \
                (bf16_t)(h * __builtin_amdgcn_rcpf(1.0f + __builtin_amdgcn_exp2f(-1.44269504f * h))); \
            float h2 = acc1[g];                                                    \
            s_H[(row + 32) * HSTR + col] =                                         \
                (bf16_t)(h2 * __builtin_amdgcn_rcpf(1.0f + __builtin_amdgcn_exp2f(-1.44269504f * h2))); \
        }                                                                          \
    } while (0)

// ---------------- fused main kernel ----------------
// Round-1 structure (4 blocks/CU), but msg_x/pos epilogues are DEFERRED to the
// very end: all 6 barriers see only LDS traffic; the atomic burst issues once,
// after the last barrier, overlapping the next block's staging.
__global__ __launch_bounds__(256, 4)
void egnn_main(const float* __restrict__ x, const float* __restrict__ pos,
               const float* __restrict__ ea, const int* __restrict__ eidx,
               const float* __restrict__ b2x, const float* __restrict__ b2p,
               const float* __restrict__ b2e,
               const bf16_t* __restrict__ wf, const bf16_t* __restrict__ xbf,
               float* __restrict__ aggx, float* __restrict__ aggpos,
               float* __restrict__ eup, int N, int E)
{
    __shared__ __align__(16) bf16_t s_comb[TILE_E * CSTR];
    __shared__ __align__(16) bf16_t s_H[TILE_E * HSTR];
    __shared__ float s_rel[TILE_E][3];
    __shared__ int s_col[TILE_E];

    const int tid = threadIdx.x;
    const int lane = tid & 63;
    const int wv = tid >> 6;        // 0..3
    const long e0 = (long)blockIdx.x * TILE_E;

    // ---- Phase 1a: indices, rel_pos, dist_sq, bias-one, K-pad ----
    if (tid < TILE_E) {
        long e = e0 + tid;
        int r = 0, c = 0;
        if (e < E) { r = eidx[e]; c = eidx[(long)E + e]; }
        s_col[tid] = c;
        float ax = 0.f, ay = 0.f, az = 0.f;
        if (e < E) {
            const float* pr = pos + (long)r * 3;
            const float* pc = pos + (long)c * 3;
            ax = pr[0] - pc[0]; ay = pr[1] - pc[1]; az = pr[2] - pc[2];
        }
        s_rel[tid][0] = ax; s_rel[tid][1] = ay; s_rel[tid][2] = az;
        bf16_t* cr = s_comb + tid * CSTR;
        cr[144] = (bf16_t)(ax * ax + ay * ay + az * az);
        cr[145] = (bf16_t)1.0f;   // bias row (W1 frag k==145 holds b1)
#pragma unroll
        for (int p = 146; p < 160; ++p) cr[p] = (bf16_t)0.0f;
    }

    // ---- Phase 1b: x[row], x[col], edge_attr -> combined (bf16) ----
    {
        const int el = tid >> 2, q = tid & 3;   // 4 threads per edge
        long e = e0 + el;
        int r = 0, c = 0;
        if (e < E) { r = eidx[e]; c = eidx[(long)E + e]; }
        bf16_t* dst = s_comb + el * CSTR;
        if (xbf) {
            const uint4* pr = (const uint4*)(xbf + (long)r * 64) + q * 2;
            const uint4* pc = (const uint4*)(xbf + (long)c * 64) + q * 2;
            uint4 a0 = pr[0], a1 = pr[1], c0 = pc[0], c1 = pc[1];
            uint4* d0 = (uint4*)(dst + q * 16);
            d0[0] = a0; d0[1] = a1;
            uint4* d1 = (uint4*)(dst + 64 + q * 16);
            d1[0] = c0; d1[1] = c1;
        } else {
            const float4* pr = (const float4*)(x + (long)r * 64) + q * 4;
            const float4* pc = (const float4*)(x + (long)c * 64) + q * 4;
            bf16_t* d0 = dst + q * 16;
            bf16_t* d1 = dst + 64 + q * 16;
#pragma unroll
            for (int i = 0; i < 4; ++i) {
                float4 v = pr[i];
                d0[i * 4 + 0] = (bf16_t)v.x; d0[i * 4 + 1] = (bf16_t)v.y;
                d0[i * 4 + 2] = (bf16_t)v.z; d0[i * 4 + 3] = (bf16_t)v.w;
            }
#pragma unroll
            for (int i = 0; i < 4; ++i) {
                float4 v = pc[i];
                d1[i * 4 + 0] = (bf16_t)v.x; d1[i * 4 + 1] = (bf16_t)v.y;
                d1[i * 4 + 2] = (bf16_t)v.z; d1[i * 4 + 3] = (bf16_t)v.w;
            }
        }
        float4 v = {0.f, 0.f, 0.f, 0.f};
        if (e < E) v = ((const float4*)(ea + (long)e * 16))[q];
        bf16_t* da = dst + 128 + q * 4;
        da[0] = (bf16_t)v.x; da[1] = (bf16_t)v.y; da[2] = (bf16_t)v.z; da[3] = (bf16_t)v.w;
    }
    __syncthreads();   // B1: combined staged

    // ================= MLP0: msg_x =================
    L1_PHASE(0);
    __syncthreads();   // B2: H(mx) ready

    // L2_mx: [64x128]@[128x64]; wave quadrant ct2=wv&1, rt=wv>>1 — DEFERRED result
    f32x16 accm = {0.0f};
    int ocm, rbm; float biasm;
    {
        const int ct2 = wv & 1, rt = wv >> 1;
        const bf16_t* bb = wf + W2X_OFF + (long)(ct2 * 8) * 512 + lane * 8;
        const bf16_t* ar = s_H + (rt * 32 + (lane & 31)) * HSTR + (lane >> 5) * 8;
#pragma unroll
        for (int kk = 0; kk < 8; ++kk) {
            bf16x8 a = *(const bf16x8*)(ar + kk * 16);
            bf16x8 b = *(const bf16x8*)(bb + kk * 512);
            accm = __builtin_amdgcn_mfma_f32_32x32x16_bf16(a, b, accm, 0, 0, 0);
        }
        ocm = ct2 * 32 + (lane & 31);
        biasm = b2x[ocm];
        rbm = rt * 32 + 4 * (lane >> 5);
    }
    __syncthreads();   // B3: H(mx) reads done, s_H reusable

    // ================= MLP1: pos =================
    L1_PHASE(1);
    __syncthreads();   // B4: H(pos) ready

    // L2_pos: [64x128]@[128x1] via 16x16x32 — DEFERRED result; wave rt16 = wv
    f32x4 accp = {0.0f};
    {
        const bf16_t* bb = wf + W2P_OFF + lane * 8;
        const bf16_t* ar = s_H + (wv * 16 + (lane & 15)) * HSTR + (lane >> 4) * 8;
#pragma unroll
        for (int kk = 0; kk < 4; ++kk) {
            bf16x8 a = *(const bf16x8*)(ar + kk * 32);
            bf16x8 b = *(const bf16x8*)(bb + kk * 512);
            accp = __builtin_amdgcn_mfma_f32_16x16x32_bf16(a, b, accp, 0, 0, 0);
        }
    }
    __syncthreads();   // B5: H(pos) reads done

    // ================= MLP2: edge =================
    L1_PHASE(2);
    __syncthreads();   // B6: H(edge) ready (LAST barrier)

    // L2_edge: [64x128]@[128x16] via 16x16x32 — immediate coalesced stores
    {
        const bf16_t* bb = wf + W2E_OFF + lane * 8;
        bf16x8 Be[4];
#pragma unroll
        for (int kk = 0; kk < 4; ++kk) Be[kk] = *(const bf16x8*)(bb + kk * 512);
        const float bias = b2e[lane & 15];
        const bf16_t* ar = s_H + (wv * 16 + (lane & 15)) * HSTR + (lane >> 4) * 8;
        f32x4 acc4 = {0.0f};
#pragma unroll
        for (int kk = 0; kk < 4; ++kk) {
            bf16x8 a = *(const bf16x8*)(ar + kk * 32);
            acc4 = __builtin_amdgcn_mfma_f32_16x16x32_bf16(a, Be[kk], acc4, 0, 0, 0);
        }
#pragma unroll
        for (int j = 0; j < 4; ++j) {
            const int row = wv * 16 + (lane >> 4) * 4 + j;
            long e = e0 + row;
            if (e < E) eup[e * 16 + (lane & 15)] = acc4[j] + bias;
        }
    }

    // ================= deferred atomic epilogue (no trailing barrier) =================
#pragma unroll
    for (int g = 0; g < 16; ++g) {
        const int row = rbm + (g & 3) + 8 * (g >> 2);
        long e = e0 + row;
        if (e < E) atomicAdd(aggx + (long)s_col[row] * 64 + ocm, accm[g] + biasm);
    }
    if ((lane & 15) == 0) {
        const float bias = b2p[0];
#pragma unroll
        for (int j = 0; j < 4; ++j) {
            const int row = wv * 16 + (lane >> 4) * 4 + j;
            long e = e0 + row;
            if (e < E) {
                const float w = accp[j] + bias;
                const long c3 = (long)s_col[row] * 3;
                atomicAdd(aggpos + c3 + 0, w * s_rel[row][0]);
                atomicAdd(aggpos + c3 + 1, w * s_rel[row][1]);
                atomicAdd(aggpos + c3 + 2, w * s_rel[row][2]);
            }
        }
    }
}

extern "C" void kernel_launch(void* const* d_in, const int* in_sizes, int n_in,
                              void* d_out, int out_size, void* d_ws, size_t ws_size,
                              hipStream_t stream)
{
    const float* x   = (const float*)d_in[0];
    const float* pos = (const float*)d_in[1];
    const float* ea  = (const float*)d_in[2];
    const int*   eidx= (const int*)d_in[3];
    const float* W1x = (const float*)d_in[4];
    const float* b1x = (const float*)d_in[5];
    const float* W2x = (const float*)d_in[6];
    const float* b2x = (const float*)d_in[7];
    const float* W1p = (const float*)d_in[8];
    const float* b1p = (const float*)d_in[9];
    const float* W2p = (const float*)d_in[10];
    const float* b2p = (const float*)d_in[11];
    const float* W1e = (const float*)d_in[12];
    const float* b1e = (const float*)d_in[13];
    const float* W2e = (const float*)d_in[14];
    const float* b2e = (const float*)d_in[15];

    const int N = in_sizes[0] / 64;     // node count
    const int E = in_sizes[2] / 16;     // edge count

    bf16_t* wf = (bf16_t*)d_ws;
    const size_t need_xbf = (size_t)XBF_OFF * 2 + (size_t)N * 64 * 2;
    bf16_t* xbf = (ws_size >= need_xbf) ? (wf + XBF_OFF) : nullptr;

    float* aggx = (float*)d_out;
    float* aggp = aggx + (long)N * 64;
    float* eup  = aggp + (long)N * 3;

    // zero the scatter-add output regions (harness poisons d_out)
    hipMemsetAsync(d_out, 0, (size_t)(N * 64 + N * 3) * sizeof(float), stream);

    hipLaunchKernelGGL(prep_w, dim3(144), dim3(64), 0, stream,
                       W1x, b1x, W1p, b1p, W1e, b1e, W2x, W2p, W2e, wf);
    if (xbf) {
        const int n8 = (N * 64) / 8;
        hipLaunchKernelGGL(prep_x_kernel, dim3((n8 + 255) / 256), dim3(256), 0, stream,
                           x, xbf, n8);
    }
    const int tiles = (E + TILE_E - 1) / TILE_E;
    hipLaunchKernelGGL(egnn_main, dim3(tiles), dim3(256), 0, stream,
                       x, pos, ea, eidx, b2x, b2p, b2e, wf, xbf, aggx, aggp, eup, N, E);
}